// Round 4
// baseline (688.717 us; speedup 1.0000x reference)
//
#include <hip/hip_runtime.h>
#include <math.h>

// ---------------------------------------------------------------------------
// HierarchicalTimeAttention on MI355X — resident-span fused edge pass, v4.
//
//   p    = nf @ (Wq@Wk^T) + bq@Wk^T          [N,128]
//   qb_n = nf_n . (Wq bk) + bq.bk            [N]
//   counting-sort edges by src (count -> scan -> scatter, + window bsearch)
//   k_fused4: block owns nodes starting in its 64-edge window. Greedy: node
//     prefix whose edge span fits EC=60 LDS rows (leftovers re-picked), then
//       Phase A (32 edges x 8 lanes): t row global->regs, stage to LDS
//         (xor-swizzled, 8-lane mapping => conflict-free banks), attn dot vs
//         p[src], sims vs ce_lds (bank-clean), 8-lane reduce, ex=exp,
//         LDS-atomic per-(node,cluster) D,C.
//       Phase B: scl[e] = ex_e * rcp(D_c*C_c)          [parallel over span]
//       Phase C: 8 teams x 32 lanes x float4 cols: register-accumulated
//         segmented sum -> agg[n]; sw[n]=sum 1/C_c. XOR-slot reads hit all
//         32 bank groups. Empty nodes fall out as zero-trip loops.
//   out = relu( (agg @ (Wv@Wo) + sw * (bv@Wo)) * (1/nne) + bo )
//
// LDS ~38KB -> 4 blocks/CU (16 waves/CU) for the latency-bound tf gather.
// NOTE: dur_us includes ~370us of harness workspace re-poison fills.
// ---------------------------------------------------------------------------

#define NN 50000
#define NE 600000
#define DD 128
#define NC 8
#define WIN 64              // sorted-edge window per block
#define NWIN 9376           // NE/WIN + 1 (last window catches off==NE empties)
#define NBF  9377           // blockFirst entries (0..NWIN)
#define EC 60               // resident edge rows
#define NLOC 32             // max nodes per greedy sub-range
#define SCALEF 0.08838834764831845f

// ---- workspace element offsets (fp32/int32 units) ----
// zeroed region:
#define OFF_NODECNT  0          // 50000 i32
#define OFF_FILL     50000      // 50000 i32
#define OFF_MASK     100000     // 256 i32
#define ZERO_ELEMS   100256
// non-zeroed (fully written each call):
#define OFF_NODEOFF  100352     // 50000 i32
#define OFF_PARTIAL  150352     // 256 i32
#define OFF_BF       150608     // 9377 i32 (pad)
#define OFF_BQK      160000     // 128 f32
#define OFF_BVO      160128     // 128 f32
#define OFF_WQBK     160256     // 128 f32
#define OFF_C0       160384     // 1 f32 (pad 16)
#define OFF_WQK      160400     // 16384 f32
#define OFF_WVO      176784     // 16384 f32
#define OFF_QB       193168     // 50000 f32
#define OFF_SORTED   243168     // 600000 i32
#define OFF_SRCS     843168     // 600000 i32
#define OFF_SW       1443168    // 50000 f32
#define OFF_P        1493168    // 6,400,000 f32 (agg aliases p: row n written only
                                //  by its owner block after all reads of p[n])
// total: 7,893,168 elems = ~31.6 MB

// --- precompute Wqk = Wq@Wk^T, Wvo = Wv@Wo, bqk, bvo, wqbk, c0
//     + (folded) edge-count histogram over src nodes ---
__global__ __launch_bounds__(256) void k_pre_count(
    const float* __restrict__ Wq, const float* __restrict__ bq,
    const float* __restrict__ Wk, const float* __restrict__ bk,
    const float* __restrict__ Wv, const float* __restrict__ bv,
    const float* __restrict__ Wo, const int* __restrict__ ei,
    int* __restrict__ node_cnt,
    float* __restrict__ Wqk, float* __restrict__ bqk,
    float* __restrict__ Wvo, float* __restrict__ bvo,
    float* __restrict__ wqbk, float* __restrict__ c0) {
  int bid = blockIdx.x, t = threadIdx.x;
  if (bid >= 129) {   // edge-count part: no barriers on this path
    long e = (long)(bid - 129) * 256 + t;
    if (e < NE) atomicAdd(&node_cnt[ei[e]], 1);
    return;
  }
  __shared__ float rq[DD], rv[DD];
  int b = bid;
  if (b < DD) {
    if (t < DD) { rq[t] = Wq[b * DD + t]; rv[t] = Wv[b * DD + t]; }
    __syncthreads();
    if (t < DD) {
      float aq = 0.f, av = 0.f;
      for (int j = 0; j < DD; j++) {
        aq += rq[j] * Wk[t * DD + j];   // Wqk[b,t] = Wq row b . Wk row t
        av += rv[j] * Wo[j * DD + t];   // Wvo[b,t] = Wv row b . Wo col t
      }
      Wqk[b * DD + t] = aq;
      Wvo[b * DD + t] = av;
    }
  } else {
    if (t < DD) {
      float a1 = 0.f, a2 = 0.f, a3 = 0.f;
      for (int j = 0; j < DD; j++) {
        a1 += bq[j] * Wk[t * DD + j];
        a2 += bv[j] * Wo[j * DD + t];
        a3 += Wq[t * DD + j] * bk[j];
      }
      bqk[t] = a1; bvo[t] = a2; wqbk[t] = a3;
      if (t == 0) {
        float s = 0.f;
        for (int j = 0; j < DD; j++) s += bq[j] * bk[j];
        *c0 = s;
      }
    }
  }
}

// --- p = nf @ Wqk + bqk ; qb = nf . wqbk + c0 --- (64-row tiles, 256 thr)
__global__ __launch_bounds__(256) void k_p(
    const float* __restrict__ nf, const float* __restrict__ Wqk,
    const float* __restrict__ bqk, const float* __restrict__ wqbk,
    const float* __restrict__ c0p,
    float* __restrict__ p, float* __restrict__ qb) {
  __shared__ float a_lds[64 * DD];
  __shared__ float wb_lds[DD];
  int t = threadIdx.x;
  long row0 = (long)blockIdx.x * 64;
  for (int it = 0; it < 8; it++) {
    int idx = (it * 256 + t) * 4;
    long r = row0 + idx / DD;
    float4 v = {0.f, 0.f, 0.f, 0.f};
    if (r < NN) v = *(const float4*)(nf + r * DD + (idx % DD));
    *(float4*)(a_lds + idx) = v;
  }
  if (t < DD) wb_lds[t] = wqbk[t];
  __syncthreads();
  int cg = t % 32, rg = t / 32;
  int col0 = cg * 4, r0 = rg * 8;
  float acc[8][4]; float qacc[8];
  for (int r = 0; r < 8; r++) { qacc[r] = 0.f; for (int c = 0; c < 4; c++) acc[r][c] = 0.f; }
  for (int k = 0; k < DD; k++) {
    float4 b4 = *(const float4*)(Wqk + k * DD + col0);
    float wbk = wb_lds[k];
    for (int r = 0; r < 8; r++) {
      float a = a_lds[(r0 + r) * DD + k];
      acc[r][0] += a * b4.x; acc[r][1] += a * b4.y;
      acc[r][2] += a * b4.z; acc[r][3] += a * b4.w;
      qacc[r] += a * wbk;
    }
  }
  float4 bq4 = *(const float4*)(bqk + col0);
  float c0v = *c0p;
  for (int r = 0; r < 8; r++) {
    long row = row0 + r0 + r;
    if (row < NN) {
      float4 o;
      o.x = acc[r][0] + bq4.x; o.y = acc[r][1] + bq4.y;
      o.z = acc[r][2] + bq4.z; o.w = acc[r][3] + bq4.w;
      *(float4*)(p + row * DD + col0) = o;
      if (cg == 0) qb[row] = qacc[r] + c0v;
    }
  }
}

// --- prefix scan of node_cnt (3 kernels) ---
__global__ __launch_bounds__(256) void k_scan1(const int* __restrict__ node_cnt,
                                               int* __restrict__ partial) {
  int i = blockIdx.x * 256 + threadIdx.x;
  int v = (i < NN) ? node_cnt[i] : 0;
  for (int o = 1; o < 64; o <<= 1) v += __shfl_xor(v, o);
  __shared__ int wsum[4];
  if ((threadIdx.x & 63) == 0) wsum[threadIdx.x >> 6] = v;
  __syncthreads();
  if (threadIdx.x == 0) partial[blockIdx.x] = wsum[0] + wsum[1] + wsum[2] + wsum[3];
}

__global__ __launch_bounds__(256) void k_scan2(int* __restrict__ partial) {
  __shared__ int s[256];
  int t = threadIdx.x;
  int v = (t < 196) ? partial[t] : 0;
  s[t] = v;
  __syncthreads();
  for (int o = 1; o < 256; o <<= 1) {
    int add = (t >= o) ? s[t - o] : 0;
    __syncthreads();
    s[t] += add;
    __syncthreads();
  }
  if (t < 196) partial[t] = s[t] - v;  // exclusive
}

__global__ __launch_bounds__(256) void k_scan3(const int* __restrict__ node_cnt,
                                               const int* __restrict__ partial,
                                               int* __restrict__ node_off) {
  __shared__ int s[256];
  int t = threadIdx.x;
  int i = blockIdx.x * 256 + t;
  int v = (i < NN) ? node_cnt[i] : 0;
  s[t] = v;
  __syncthreads();
  for (int o = 1; o < 256; o <<= 1) {
    int add = (t >= o) ? s[t - o] : 0;
    __syncthreads();
    s[t] += add;
    __syncthreads();
  }
  if (i < NN) node_off[i] = partial[blockIdx.x] + s[t] - v;
}

// --- counting-sort scatter (+ folded window lower_bound table) ---
#define EDGE_BLKS 2344      // ceil(NE/256)
#define BS_BLKS   37        // ceil(NBF/256)
__global__ __launch_bounds__(256) void k_scatter(const int* __restrict__ ei,
                                                 const int* __restrict__ node_off,
                                                 int* __restrict__ fill,
                                                 int* __restrict__ sorted,
                                                 int* __restrict__ srcs,
                                                 int* __restrict__ blockFirst) {
  int bid = blockIdx.x, t = threadIdx.x;
  if (bid >= EDGE_BLKS) {
    int w = (bid - EDGE_BLKS) * 256 + t;
    if (w < NBF) {
      int v = w * WIN, lo = 0, hi = NN;
      while (lo < hi) { int mid = (lo + hi) >> 1; if (node_off[mid] < v) lo = mid + 1; else hi = mid; }
      blockFirst[w] = lo;   // first n with off[n] >= w*WIN
    }
    return;
  }
  long e = (long)bid * 256 + t;
  if (e < NE) {
    int s = ei[e];
    int pos = node_off[s] + atomicAdd(&fill[s], 1);
    sorted[pos] = (int)e;
    srcs[pos] = s;
  }
}

// --- Phase A worker: one edge, 8 lanes (j=0..7); lane j owns slots i*8+j.
// Staging bank-start = 4*(j^e7): per-edge permutation of 8 bank groups ->
// conflict-free. ce reads bank-start = 4*j, broadcast across edges. ---
__device__ __forceinline__ void phase_a(
    const float* __restrict__ tf, const float* __restrict__ p,
    const float* ce_lds, float* t_lds, float* exf_sh, int* cli_sh,
    float* D_sh, int* C_sh,
    int slot, int j, int eid, int src, int lnode, float qbv,
    bool doStage, bool doDC) {
  const float* trow = tf + (long)eid * DD;
  float4 tv[4];
  #pragma unroll
  for (int i = 0; i < 4; i++) tv[i] = *(const float4*)(trow + (i * 8 + j) * 4);
  if (doStage) {
    int e7 = slot & 7;
    #pragma unroll
    for (int i = 0; i < 4; i++)
      *(float4*)(t_lds + slot * DD + (((i * 8 + j) ^ e7) << 2)) = tv[i];
  }
  const float* prow = p + (long)src * DD;
  float a = 0.f;
  #pragma unroll
  for (int i = 0; i < 4; i++) {
    float4 pv = *(const float4*)(prow + (i * 8 + j) * 4);
    a += tv[i].x * pv.x + tv[i].y * pv.y + tv[i].z * pv.z + tv[i].w * pv.w;
  }
  float sims[NC];
  #pragma unroll
  for (int c = 0; c < NC; c++) {
    const float* cr = ce_lds + c * DD;
    float s = 0.f;
    #pragma unroll
    for (int i = 0; i < 4; i++) {
      float4 cv = *(const float4*)(cr + (i * 8 + j) * 4);
      s += tv[i].x * cv.x + tv[i].y * cv.y + tv[i].z * cv.z + tv[i].w * cv.w;
    }
    sims[c] = s;
  }
  #pragma unroll
  for (int c = 0; c < NC; c++) {
    sims[c] += __shfl_xor(sims[c], 1);
    sims[c] += __shfl_xor(sims[c], 2);
    sims[c] += __shfl_xor(sims[c], 4);
  }
  a += __shfl_xor(a, 1);
  a += __shfl_xor(a, 2);
  a += __shfl_xor(a, 4);
  if (j == 0) {
    float best = sims[0]; int bc = 0;
    #pragma unroll
    for (int c = 1; c < NC; c++) if (sims[c] > best) { best = sims[c]; bc = c; }
    float ex = expf((a + qbv) * SCALEF);
    exf_sh[slot] = ex; cli_sh[slot] = bc;
    if (doDC) {
      atomicAdd(&D_sh[lnode * NC + bc], ex);
      atomicAdd(&C_sh[lnode * NC + bc], 1);
    }
  }
}

// --- fused edge pass: resident span, parallel scale, register aggregation ---
__global__ __launch_bounds__(256) void k_fused4(
    const float* __restrict__ tf, const int* __restrict__ sorted,
    const int* __restrict__ srcs, const int* __restrict__ node_off,
    const int* __restrict__ node_cnt, const int* __restrict__ blockFirst,
    const float* __restrict__ ce, const float* __restrict__ p,
    const float* __restrict__ qb, int* __restrict__ maskArr,
    float* __restrict__ agg, float* __restrict__ sw) {
  __shared__ float t_lds[EC * DD];      // 30 KB (xor-swizzled float4 slots)
  __shared__ float ce_lds[NC * DD];     // 4 KB
  __shared__ float exf_sh[EC];
  __shared__ float scl_sh[EC];
  __shared__ int   cli_sh[EC];
  __shared__ int   offL_sh[NLOC];
  __shared__ int   cntL_sh[NLOC];
  __shared__ float qb_sh[NLOC];
  __shared__ float D_sh[NLOC * NC];     // 1 KB
  __shared__ int   C_sh[NLOC * NC];     // 1 KB
  __shared__ int   ctrl[4];             // 0:nN 1:span 2:eb

  int t = threadIdx.x, b = blockIdx.x;
  int fn = blockFirst[b], ln = blockFirst[b + 1] - 1;
  if (fn >= NN || ln < fn) return;   // window owns no node starts

  *(float4*)(ce_lds + t * 4) = *(const float4*)(ce + t * 4);

  int el8 = t >> 3, j8 = t & 7;            // Phase A: 32 edges x 8 lanes
  int team = t >> 5, c4 = t & 31;          // Phase C: 8 teams x 32 float4-cols
  int msk = 0;

  int s0 = fn;
  while (s0 <= ln) {
    // ---- wave 0: greedy node-prefix pick + per-node staging ----
    if (t < 64) {
      int offv = 0, cntv = 0; bool fit = false;
      bool valid = (t < NLOC && s0 + t <= ln);
      if (valid) { offv = node_off[s0 + t]; cntv = node_cnt[s0 + t]; }
      int off0 = __shfl(offv, 0);
      if (valid) {
        fit = (offv - off0 + cntv) <= EC;
        offL_sh[t] = offv - off0; cntL_sh[t] = cntv; qb_sh[t] = qb[s0 + t];
      }
      unsigned long long bm = __ballot(fit);
      int pref = (int)__popcll(bm);        // fit is a monotone prefix
      if (t == 0) { ctrl[0] = pref; ctrl[2] = off0; }
      if (pref > 0 && t == pref - 1) ctrl[1] = offv - off0 + cntv;  // span
    }
    for (int i = t; i < NLOC * NC; i += 256) { D_sh[i] = 0.f; C_sh[i] = 0; }
    __syncthreads();
    int nN = ctrl[0], eb = ctrl[2];

    if (nN == 0) {
      // ---- pathological single node with > EC edges: chunked two-pass ----
      int cnt = cntL_sh[0];
      float qbv0 = qb_sh[0];
      for (int c0 = 0; c0 < cnt; c0 += 32) {        // pass 1: D,C only
        int el = c0 + el8;
        if (el < cnt)
          phase_a(tf, p, ce_lds, t_lds, exf_sh, cli_sh, D_sh, C_sh,
                  el8, j8, sorted[eb + el], s0, 0, qbv0, false, true);
      }
      __syncthreads();
      float4 r = {0.f, 0.f, 0.f, 0.f};
      for (int c0 = 0; c0 < cnt; c0 += EC) {        // pass 2: aggregate
        int m = cnt - c0; if (m > EC) m = EC;
        for (int r0 = 0; r0 < m; r0 += 32) {
          int sl = r0 + el8;
          if (sl < m)
            phase_a(tf, p, ce_lds, t_lds, exf_sh, cli_sh, D_sh, C_sh,
                    sl, j8, sorted[eb + c0 + sl], s0, 0, qbv0, true, false);
        }
        __syncthreads();
        if (t < m) {
          int c = cli_sh[t];
          scl_sh[t] = exf_sh[t] * __builtin_amdgcn_rcpf(D_sh[c] * (float)C_sh[c]);
        }
        __syncthreads();
        for (int e = team; e < m; e += 8) {
          float s = scl_sh[e];
          const float4 tv = *(const float4*)(t_lds + e * DD + ((c4 ^ (e & 7)) << 2));
          r.x += s * tv.x; r.y += s * tv.y; r.z += s * tv.z; r.w += s * tv.w;
        }
        __syncthreads();
      }
      *(float4*)(t_lds + team * DD + c4 * 4) = r;   // 8-team combine
      __syncthreads();
      if (t < DD) {
        float acc = 0.f;
        #pragma unroll
        for (int tm = 0; tm < 8; tm++) acc += t_lds[tm * DD + t];
        agg[(long)s0 * DD + t] = acc;
      }
      if (t == 0) {
        float ssw = 0.f; int mk = 0;
        #pragma unroll
        for (int c = 0; c < NC; c++) {
          int cc = C_sh[c];
          if (cc > 0) { mk |= 1 << c; ssw += __builtin_amdgcn_rcpf((float)cc); }
        }
        sw[s0] = ssw; msk |= mk;
      }
      __syncthreads();
      s0 += 1;
      continue;
    }

    int span = ctrl[1];

    // ---- Phase A: all span edges, 8 lanes each, 32 edges/pass ----
    for (int r0 = 0; r0 < span; r0 += 32) {
      int el = r0 + el8;
      if (el < span) {
        int src = srcs[eb + el];     // 8 lanes same addr -> broadcast
        phase_a(tf, p, ce_lds, t_lds, exf_sh, cli_sh, D_sh, C_sh,
                el, j8, sorted[eb + el], src, src - s0, qb_sh[src - s0],
                true, true);
      }
    }
    __syncthreads();

    // ---- Phase B: parallel scale ----
    if (t < span) {
      int l = (srcs[eb + t] - s0) * NC + cli_sh[t];
      scl_sh[t] = exf_sh[t] * __builtin_amdgcn_rcpf(D_sh[l] * (float)C_sh[l]);
    }
    __syncthreads();

    // ---- Phase C: register-accumulated segmented sums, float4 columns ----
    for (int k = team; k < nN; k += 8) {
      float4 r = {0.f, 0.f, 0.f, 0.f};
      int e1 = offL_sh[k] + cntL_sh[k];
      for (int e = offL_sh[k]; e < e1; e++) {
        float s = scl_sh[e];
        const float4 tv = *(const float4*)(t_lds + e * DD + ((c4 ^ (e & 7)) << 2));
        r.x += s * tv.x; r.y += s * tv.y; r.z += s * tv.z; r.w += s * tv.w;
      }
      long n = s0 + k;
      *(float4*)(agg + n * DD + c4 * 4) = r;
      if (c4 == 0) {
        float ssw = 0.f; int mk = 0;
        #pragma unroll
        for (int c = 0; c < NC; c++) {
          int cc = C_sh[k * NC + c];
          if (cc > 0) { mk |= 1 << c; ssw += __builtin_amdgcn_rcpf((float)cc); }
        }
        sw[n] = ssw; msk |= mk;
      }
    }
    __syncthreads();
    s0 += nN;
  }
  if ((t & 31) == 0 && msk) atomicOr(&maskArr[b & 255], msk);
}

// --- out = relu((agg @ Wvo + sw*bvo) * inv_nne + bo); inv_nne from maskArr ---
__global__ __launch_bounds__(256) void k_out(
    const float* __restrict__ agg, const float* __restrict__ Wvo,
    const float* __restrict__ bvo, const float* __restrict__ sw,
    const float* __restrict__ bo, const int* __restrict__ maskArr,
    float* __restrict__ out) {
  __shared__ float a_lds[64 * DD];
  __shared__ float sw_lds[64];
  __shared__ int morw[4];
  int t = threadIdx.x;
  int mv = maskArr[t];
  for (int o = 1; o < 64; o <<= 1) mv |= __shfl_xor(mv, o);
  if ((t & 63) == 0) morw[t >> 6] = mv;
  long row0 = (long)blockIdx.x * 64;
  for (int it = 0; it < 8; it++) {
    int idx = (it * 256 + t) * 4;
    long r = row0 + idx / DD;
    float4 v = {0.f, 0.f, 0.f, 0.f};
    if (r < NN) v = *(const float4*)(agg + r * DD + (idx % DD));
    *(float4*)(a_lds + idx) = v;
  }
  if (t < 64) {
    long r = row0 + t;
    sw_lds[t] = (r < NN) ? sw[r] : 0.f;
  }
  __syncthreads();
  int full = morw[0] | morw[1] | morw[2] | morw[3];
  int nne = __popc(full); if (nne == 0) nne = 1;
  float inv = 1.0f / (float)nne;
  int cg = t % 32, rg = t / 32;
  int col0 = cg * 4, r0 = rg * 8;
  float acc[8][4];
  for (int r = 0; r < 8; r++) for (int c = 0; c < 4; c++) acc[r][c] = 0.f;
  for (int k = 0; k < DD; k++) {
    float4 b4 = *(const float4*)(Wvo + k * DD + col0);
    for (int r = 0; r < 8; r++) {
      float a = a_lds[(r0 + r) * DD + k];
      acc[r][0] += a * b4.x; acc[r][1] += a * b4.y;
      acc[r][2] += a * b4.z; acc[r][3] += a * b4.w;
    }
  }
  float4 bv4 = *(const float4*)(bvo + col0);
  float4 bo4 = *(const float4*)(bo + col0);
  for (int r = 0; r < 8; r++) {
    long row = row0 + r0 + r;
    if (row < NN) {
      float s = sw_lds[r0 + r];
      float4 o;
      o.x = fmaxf((acc[r][0] + s * bv4.x) * inv + bo4.x, 0.f);
      o.y = fmaxf((acc[r][1] + s * bv4.y) * inv + bo4.y, 0.f);
      o.z = fmaxf((acc[r][2] + s * bv4.z) * inv + bo4.z, 0.f);
      o.w = fmaxf((acc[r][3] + s * bv4.w) * inv + bo4.w, 0.f);
      *(float4*)(out + row * DD + col0) = o;
    }
  }
}

extern "C" void kernel_launch(void* const* d_in, const int* in_sizes, int n_in,
                              void* d_out, int out_size, void* d_ws, size_t ws_size,
                              hipStream_t stream) {
  const float* nf = (const float*)d_in[0];
  const float* tf = (const float*)d_in[1];
  // d_in[2] = context_feat: unused by the reference
  const int*   ei = (const int*)d_in[3];   // row 0 = src
  const float* Wq = (const float*)d_in[4];
  const float* bq = (const float*)d_in[5];
  const float* Wk = (const float*)d_in[6];
  const float* bk = (const float*)d_in[7];
  const float* Wv = (const float*)d_in[8];
  const float* bv = (const float*)d_in[9];
  const float* ce = (const float*)d_in[10];
  const float* Wo = (const float*)d_in[11];
  const float* bo = (const float*)d_in[12];
  float* out = (float*)d_out;

  float* ws  = (float*)d_ws;
  int*   node_cnt = (int*)(ws + OFF_NODECNT);
  int*   fill     = (int*)(ws + OFF_FILL);
  int*   maskArr  = (int*)(ws + OFF_MASK);
  int*   node_off = (int*)(ws + OFF_NODEOFF);
  int*   partial  = (int*)(ws + OFF_PARTIAL);
  int*   blockFirst = (int*)(ws + OFF_BF);
  float* bqk      = ws + OFF_BQK;
  float* bvo      = ws + OFF_BVO;
  float* wqbk     = ws + OFF_WQBK;
  float* c0       = ws + OFF_C0;
  float* Wqk      = ws + OFF_WQK;
  float* Wvo      = ws + OFF_WVO;
  float* qb       = ws + OFF_QB;
  int*   sorted   = (int*)(ws + OFF_SORTED);
  int*   srcs     = (int*)(ws + OFF_SRCS);
  float* sw       = ws + OFF_SW;
  float* p        = ws + OFF_P;   // [N,128]
  float* agg      = ws + OFF_P;   // aliased (ownership-safe)

  hipMemsetAsync(d_ws, 0, (size_t)ZERO_ELEMS * 4, stream);

  k_pre_count<<<129 + EDGE_BLKS, 256, 0, stream>>>(
      Wq, bq, Wk, bk, Wv, bv, Wo, ei, node_cnt, Wqk, bqk, Wvo, bvo, wqbk, c0);
  k_p<<<(NN + 63) / 64, 256, 0, stream>>>(nf, Wqk, bqk, wqbk, c0, p, qb);
  k_scan1<<<196, 256, 0, stream>>>(node_cnt, partial);
  k_scan2<<<1, 256, 0, stream>>>(partial);
  k_scan3<<<196, 256, 0, stream>>>(node_cnt, partial, node_off);
  k_scatter<<<EDGE_BLKS + BS_BLKS, 256, 0, stream>>>(ei, node_off, fill, sorted,
                                                     srcs, blockFirst);
  k_fused4<<<NWIN, 256, 0, stream>>>(tf, sorted, srcs, node_off, node_cnt,
                                     blockFirst, ce, p, qb, maskArr, agg, sw);
  k_out<<<(NN + 63) / 64, 256, 0, stream>>>(agg, Wvo, bvo, sw, bo, maskArr, out);
}

// Round 5
// 665.986 us; speedup vs baseline: 1.0341x; 1.0341x over previous
//
#include <hip/hip_runtime.h>
#include <math.h>

// ---------------------------------------------------------------------------
// HierarchicalTimeAttention on MI355X — resident-span fused edge pass, v5.
//
//   p    = nf @ (Wq@Wk^T) + bq@Wk^T          [N,128]
//   qb_n = nf_n . (Wq bk) + bq.bk            [N]
//   counting-sort edges by src (count -> scan -> scatter, + window bsearch)
//   k_fused5: block owns nodes starting in its 64-edge window. Greedy: node
//     prefix whose edge span fits EC=70 LDS rows, then
//       Phase A (16 edges x 16 lanes, tf rows software-pipelined 1 ahead):
//         t row global->regs, stage to LDS (xor-swizzled), attn dot vs
//         p[src], sims vs ce held in VGPRs (64 regs/lane, zero LDS reads),
//         16-lane shuffle reduce, ex=exp, LDS-atomic per-(node,cluster) D,C.
//       Phase B: scl[e] = ex_e * rcp(D_c*C_c)          [parallel over span]
//       Phase C: 8 teams x 32 lanes x float4 cols: register-accumulated
//         segmented sum -> agg[n]; sw[n]=sum 1/C_c. XOR-slot reads hit all
//         32 bank groups. Empty nodes fall out as zero-trip loops.
//   out = relu( (agg @ (Wv@Wo) + sw * (bv@Wo)) * (1/nne) + bo )
//
// LDS ~39KB -> 4 blocks/CU; __launch_bounds__(256,4) pins VGPR<=128.
// NOTE: dur_us includes ~370us of harness workspace re-poison fills.
// ---------------------------------------------------------------------------

#define NN 50000
#define NE 600000
#define DD 128
#define NC 8
#define WIN 64              // sorted-edge window per block
#define NWIN 9376           // NE/WIN + 1 (last window catches off==NE empties)
#define NBF  9377           // blockFirst entries (0..NWIN)
#define EC 70               // resident edge rows
#define NLOC 32             // max nodes per greedy sub-range
#define SCALEF 0.08838834764831845f

// ---- workspace element offsets (fp32/int32 units) ----
// zeroed region:
#define OFF_NODECNT  0          // 50000 i32
#define OFF_FILL     50000      // 50000 i32
#define OFF_MASK     100000     // 256 i32
#define ZERO_ELEMS   100256
// non-zeroed (fully written each call):
#define OFF_NODEOFF  100352     // 50000 i32
#define OFF_PARTIAL  150352     // 256 i32
#define OFF_BF       150608     // 9377 i32 (pad)
#define OFF_BQK      160000     // 128 f32
#define OFF_BVO      160128     // 128 f32
#define OFF_WQBK     160256     // 128 f32
#define OFF_C0       160384     // 1 f32 (pad 16)
#define OFF_WQK      160400     // 16384 f32
#define OFF_WVO      176784     // 16384 f32
#define OFF_QB       193168     // 50000 f32
#define OFF_SORTED   243168     // 600000 i32
#define OFF_SRCS     843168     // 600000 i32
#define OFF_SW       1443168    // 50000 f32
#define OFF_P        1493168    // 6,400,000 f32 (agg aliases p: row n written only
                                //  by its owner block after all reads of p[n])
// total: 7,893,168 elems = ~31.6 MB

__device__ __forceinline__ float dot4(float4 a, float4 b) {
  return a.x * b.x + a.y * b.y + a.z * b.z + a.w * b.w;
}

// --- precompute Wqk = Wq@Wk^T, Wvo = Wv@Wo, bqk, bvo, wqbk, c0
//     + (folded) edge-count histogram over src nodes ---
__global__ __launch_bounds__(256) void k_pre_count(
    const float* __restrict__ Wq, const float* __restrict__ bq,
    const float* __restrict__ Wk, const float* __restrict__ bk,
    const float* __restrict__ Wv, const float* __restrict__ bv,
    const float* __restrict__ Wo, const int* __restrict__ ei,
    int* __restrict__ node_cnt,
    float* __restrict__ Wqk, float* __restrict__ bqk,
    float* __restrict__ Wvo, float* __restrict__ bvo,
    float* __restrict__ wqbk, float* __restrict__ c0) {
  int bid = blockIdx.x, t = threadIdx.x;
  if (bid >= 129) {   // edge-count part: no barriers on this path
    long e = (long)(bid - 129) * 256 + t;
    if (e < NE) atomicAdd(&node_cnt[ei[e]], 1);
    return;
  }
  __shared__ float rq[DD], rv[DD];
  int b = bid;
  if (b < DD) {
    if (t < DD) { rq[t] = Wq[b * DD + t]; rv[t] = Wv[b * DD + t]; }
    __syncthreads();
    if (t < DD) {
      float aq = 0.f, av = 0.f;
      for (int j = 0; j < DD; j++) {
        aq += rq[j] * Wk[t * DD + j];   // Wqk[b,t] = Wq row b . Wk row t
        av += rv[j] * Wo[j * DD + t];   // Wvo[b,t] = Wv row b . Wo col t
      }
      Wqk[b * DD + t] = aq;
      Wvo[b * DD + t] = av;
    }
  } else {
    if (t < DD) {
      float a1 = 0.f, a2 = 0.f, a3 = 0.f;
      for (int j = 0; j < DD; j++) {
        a1 += bq[j] * Wk[t * DD + j];
        a2 += bv[j] * Wo[j * DD + t];
        a3 += Wq[t * DD + j] * bk[j];
      }
      bqk[t] = a1; bvo[t] = a2; wqbk[t] = a3;
      if (t == 0) {
        float s = 0.f;
        for (int j = 0; j < DD; j++) s += bq[j] * bk[j];
        *c0 = s;
      }
    }
  }
}

// --- p = nf @ Wqk + bqk ; qb = nf . wqbk + c0 --- (64-row tiles, 256 thr)
__global__ __launch_bounds__(256) void k_p(
    const float* __restrict__ nf, const float* __restrict__ Wqk,
    const float* __restrict__ bqk, const float* __restrict__ wqbk,
    const float* __restrict__ c0p,
    float* __restrict__ p, float* __restrict__ qb) {
  __shared__ float a_lds[64 * DD];
  __shared__ float wb_lds[DD];
  int t = threadIdx.x;
  long row0 = (long)blockIdx.x * 64;
  for (int it = 0; it < 8; it++) {
    int idx = (it * 256 + t) * 4;
    long r = row0 + idx / DD;
    float4 v = {0.f, 0.f, 0.f, 0.f};
    if (r < NN) v = *(const float4*)(nf + r * DD + (idx % DD));
    *(float4*)(a_lds + idx) = v;
  }
  if (t < DD) wb_lds[t] = wqbk[t];
  __syncthreads();
  int cg = t % 32, rg = t / 32;
  int col0 = cg * 4, r0 = rg * 8;
  float acc[8][4]; float qacc[8];
  for (int r = 0; r < 8; r++) { qacc[r] = 0.f; for (int c = 0; c < 4; c++) acc[r][c] = 0.f; }
  for (int k = 0; k < DD; k++) {
    float4 b4 = *(const float4*)(Wqk + k * DD + col0);
    float wbk = wb_lds[k];
    for (int r = 0; r < 8; r++) {
      float a = a_lds[(r0 + r) * DD + k];
      acc[r][0] += a * b4.x; acc[r][1] += a * b4.y;
      acc[r][2] += a * b4.z; acc[r][3] += a * b4.w;
      qacc[r] += a * wbk;
    }
  }
  float4 bq4 = *(const float4*)(bqk + col0);
  float c0v = *c0p;
  for (int r = 0; r < 8; r++) {
    long row = row0 + r0 + r;
    if (row < NN) {
      float4 o;
      o.x = acc[r][0] + bq4.x; o.y = acc[r][1] + bq4.y;
      o.z = acc[r][2] + bq4.z; o.w = acc[r][3] + bq4.w;
      *(float4*)(p + row * DD + col0) = o;
      if (cg == 0) qb[row] = qacc[r] + c0v;
    }
  }
}

// --- prefix scan of node_cnt (3 kernels) ---
__global__ __launch_bounds__(256) void k_scan1(const int* __restrict__ node_cnt,
                                               int* __restrict__ partial) {
  int i = blockIdx.x * 256 + threadIdx.x;
  int v = (i < NN) ? node_cnt[i] : 0;
  for (int o = 1; o < 64; o <<= 1) v += __shfl_xor(v, o);
  __shared__ int wsum[4];
  if ((threadIdx.x & 63) == 0) wsum[threadIdx.x >> 6] = v;
  __syncthreads();
  if (threadIdx.x == 0) partial[blockIdx.x] = wsum[0] + wsum[1] + wsum[2] + wsum[3];
}

__global__ __launch_bounds__(256) void k_scan2(int* __restrict__ partial) {
  __shared__ int s[256];
  int t = threadIdx.x;
  int v = (t < 196) ? partial[t] : 0;
  s[t] = v;
  __syncthreads();
  for (int o = 1; o < 256; o <<= 1) {
    int add = (t >= o) ? s[t - o] : 0;
    __syncthreads();
    s[t] += add;
    __syncthreads();
  }
  if (t < 196) partial[t] = s[t] - v;  // exclusive
}

__global__ __launch_bounds__(256) void k_scan3(const int* __restrict__ node_cnt,
                                               const int* __restrict__ partial,
                                               int* __restrict__ node_off) {
  __shared__ int s[256];
  int t = threadIdx.x;
  int i = blockIdx.x * 256 + t;
  int v = (i < NN) ? node_cnt[i] : 0;
  s[t] = v;
  __syncthreads();
  for (int o = 1; o < 256; o <<= 1) {
    int add = (t >= o) ? s[t - o] : 0;
    __syncthreads();
    s[t] += add;
    __syncthreads();
  }
  if (i < NN) node_off[i] = partial[blockIdx.x] + s[t] - v;
}

// --- counting-sort scatter (+ folded window lower_bound table) ---
#define EDGE_BLKS 2344      // ceil(NE/256)
#define BS_BLKS   37        // ceil(NBF/256)
__global__ __launch_bounds__(256) void k_scatter(const int* __restrict__ ei,
                                                 const int* __restrict__ node_off,
                                                 int* __restrict__ fill,
                                                 int* __restrict__ sorted,
                                                 int* __restrict__ srcs,
                                                 int* __restrict__ blockFirst) {
  int bid = blockIdx.x, t = threadIdx.x;
  if (bid >= EDGE_BLKS) {
    int w = (bid - EDGE_BLKS) * 256 + t;
    if (w < NBF) {
      int v = w * WIN, lo = 0, hi = NN;
      while (lo < hi) { int mid = (lo + hi) >> 1; if (node_off[mid] < v) lo = mid + 1; else hi = mid; }
      blockFirst[w] = lo;   // first n with off[n] >= w*WIN
    }
    return;
  }
  long e = (long)bid * 256 + t;
  if (e < NE) {
    int s = ei[e];
    int pos = node_off[s] + atomicAdd(&fill[s], 1);
    sorted[pos] = (int)e;
    srcs[pos] = s;
  }
}

// --- Phase A worker (fallback path): one edge, 16 lanes (jA=0..15).
// Lane jA owns logical float4 slots {jA, 16+jA}; staged at slot^e7
// (per-edge permutation -> uniform banks). ce fragments live in VGPRs. ---
__device__ __forceinline__ void phase_a16(
    const float* __restrict__ tf, const float* __restrict__ p,
    const float4 (&ceg)[NC][2], float* t_lds, float* exf_sh, int* cli_sh,
    float* D_sh, int* C_sh,
    int slot, int jA, int eid, int src, int lnode, float qbv,
    bool doStage, bool doDC) {
  const float* trow = tf + (long)eid * DD;
  float4 t0 = *(const float4*)(trow + jA * 4);
  float4 t1 = *(const float4*)(trow + (16 + jA) * 4);
  if (doStage) {
    int e7 = slot & 7;
    *(float4*)(t_lds + slot * DD + ((jA ^ e7) << 2)) = t0;
    *(float4*)(t_lds + slot * DD + ((16 + (jA ^ e7)) << 2)) = t1;
  }
  const float* prow = p + (long)src * DD;
  float4 p0 = *(const float4*)(prow + jA * 4);
  float4 p1 = *(const float4*)(prow + (16 + jA) * 4);
  float a = dot4(t0, p0) + dot4(t1, p1);
  float sims[NC];
  #pragma unroll
  for (int c = 0; c < NC; c++)
    sims[c] = dot4(t0, ceg[c][0]) + dot4(t1, ceg[c][1]);
  #pragma unroll
  for (int c = 0; c < NC; c++) {
    sims[c] += __shfl_xor(sims[c], 1);
    sims[c] += __shfl_xor(sims[c], 2);
    sims[c] += __shfl_xor(sims[c], 4);
    sims[c] += __shfl_xor(sims[c], 8);
  }
  a += __shfl_xor(a, 1);
  a += __shfl_xor(a, 2);
  a += __shfl_xor(a, 4);
  a += __shfl_xor(a, 8);
  if (jA == 0) {
    float best = sims[0]; int bc = 0;
    #pragma unroll
    for (int c = 1; c < NC; c++) if (sims[c] > best) { best = sims[c]; bc = c; }
    float ex = expf((a + qbv) * SCALEF);
    exf_sh[slot] = ex; cli_sh[slot] = bc;
    if (doDC) {
      atomicAdd(&D_sh[lnode * NC + bc], ex);
      atomicAdd(&C_sh[lnode * NC + bc], 1);
    }
  }
}

// --- fused edge pass: resident span, ce-in-VGPR, pipelined tf loads ---
__global__ __launch_bounds__(256, 4) void k_fused5(
    const float* __restrict__ tf, const int* __restrict__ sorted,
    const int* __restrict__ srcs, const int* __restrict__ node_off,
    const int* __restrict__ node_cnt, const int* __restrict__ blockFirst,
    const float* __restrict__ ce, const float* __restrict__ p,
    const float* __restrict__ qb, int* __restrict__ maskArr,
    float* __restrict__ agg, float* __restrict__ sw) {
  __shared__ float t_lds[EC * DD];      // 35 KB (xor-swizzled float4 slots)
  __shared__ float exf_sh[EC];
  __shared__ float scl_sh[EC];
  __shared__ int   cli_sh[EC];
  __shared__ int   eidx_sh[EC];
  __shared__ int   srcs_sh[EC];
  __shared__ int   offL_sh[NLOC];
  __shared__ int   cntL_sh[NLOC];
  __shared__ float qb_sh[NLOC];
  __shared__ float D_sh[NLOC * NC];     // 1 KB
  __shared__ int   C_sh[NLOC * NC];     // 1 KB
  __shared__ int   ctrl[4];             // 0:nN 1:span 2:eb

  int t = threadIdx.x, b = blockIdx.x;
  int fn = blockFirst[b], ln = blockFirst[b + 1] - 1;
  if (fn >= NN || ln < fn) return;   // window owns no node starts

  int elA = t >> 4, jA = t & 15;           // Phase A: 16 edges x 16 lanes
  int team = t >> 5, c4 = t & 31;          // Phase C: 8 teams x 32 float4-cols
  int msk = 0;

  // cluster embeddings -> registers (once per kernel): 8 clusters x 2 float4
  float4 ceg[NC][2];
  #pragma unroll
  for (int c = 0; c < NC; c++) {
    ceg[c][0] = *(const float4*)(ce + c * DD + jA * 4);
    ceg[c][1] = *(const float4*)(ce + c * DD + (16 + jA) * 4);
  }

  int s0 = fn;
  while (s0 <= ln) {
    // ---- wave 0: greedy node-prefix pick + per-node staging ----
    if (t < 64) {
      int offv = 0, cntv = 0; bool fit = false;
      bool valid = (t < NLOC && s0 + t <= ln);
      if (valid) { offv = node_off[s0 + t]; cntv = node_cnt[s0 + t]; }
      int off0 = __shfl(offv, 0);
      if (valid) {
        fit = (offv - off0 + cntv) <= EC;
        offL_sh[t] = offv - off0; cntL_sh[t] = cntv; qb_sh[t] = qb[s0 + t];
      }
      unsigned long long bm = __ballot(fit);
      int pref = (int)__popcll(bm);        // fit is a monotone prefix
      if (t == 0) { ctrl[0] = pref; ctrl[2] = off0; }
      if (pref > 0 && t == pref - 1) ctrl[1] = offv - off0 + cntv;  // span
    }
    for (int i = t; i < NLOC * NC; i += 256) { D_sh[i] = 0.f; C_sh[i] = 0; }
    __syncthreads();
    int nN = ctrl[0], eb = ctrl[2];

    if (nN == 0) {
      // ---- pathological single node with > EC edges: chunked two-pass ----
      int cnt = cntL_sh[0];
      float qbv0 = qb_sh[0];
      for (int c0 = 0; c0 < cnt; c0 += 16) {        // pass 1: D,C only
        int el = c0 + elA;
        if (el < cnt)
          phase_a16(tf, p, ceg, t_lds, exf_sh, cli_sh, D_sh, C_sh,
                    elA, jA, sorted[eb + el], s0, 0, qbv0, false, true);
      }
      __syncthreads();
      float4 r = {0.f, 0.f, 0.f, 0.f};
      for (int c0 = 0; c0 < cnt; c0 += EC) {        // pass 2: aggregate
        int m = cnt - c0; if (m > EC) m = EC;
        for (int r0 = 0; r0 < m; r0 += 16) {
          int sl = r0 + elA;
          if (sl < m)
            phase_a16(tf, p, ceg, t_lds, exf_sh, cli_sh, D_sh, C_sh,
                      sl, jA, sorted[eb + c0 + sl], s0, 0, qbv0, true, false);
        }
        __syncthreads();
        if (t < m) {
          int c = cli_sh[t];
          scl_sh[t] = exf_sh[t] * __builtin_amdgcn_rcpf(D_sh[c] * (float)C_sh[c]);
        }
        __syncthreads();
        for (int e = team; e < m; e += 8) {
          float s = scl_sh[e];
          const float4 tv = *(const float4*)(t_lds + e * DD + ((c4 ^ (e & 7)) << 2));
          r.x += s * tv.x; r.y += s * tv.y; r.z += s * tv.z; r.w += s * tv.w;
        }
        __syncthreads();
      }
      *(float4*)(t_lds + team * DD + c4 * 4) = r;   // 8-team combine
      __syncthreads();
      if (t < DD) {
        float acc = 0.f;
        #pragma unroll
        for (int tm = 0; tm < 8; tm++) acc += t_lds[tm * DD + t];
        agg[(long)s0 * DD + t] = acc;
      }
      if (t == 0) {
        float ssw = 0.f; int mk = 0;
        #pragma unroll
        for (int c = 0; c < NC; c++) {
          int cc = C_sh[c];
          if (cc > 0) { mk |= 1 << c; ssw += __builtin_amdgcn_rcpf((float)cc); }
        }
        sw[s0] = ssw; msk |= mk;
      }
      __syncthreads();
      s0 += 1;
      continue;
    }

    int span = ctrl[1];

    // ---- stage edge ids / srcs for the span (breaks index->row dep chain) ----
    if (t < span) { eidx_sh[t] = sorted[eb + t]; srcs_sh[t] = srcs[eb + t]; }
    __syncthreads();

    // ---- Phase A: 16 edges/pass, tf rows software-pipelined 1 ahead ----
    float4 tc0 = {0.f,0.f,0.f,0.f}, tc1 = {0.f,0.f,0.f,0.f};
    if (elA < span) {
      const float* tr = tf + (long)eidx_sh[elA] * DD;
      tc0 = *(const float4*)(tr + jA * 4);
      tc1 = *(const float4*)(tr + (16 + jA) * 4);
    }
    for (int r0 = 0; r0 < span; r0 += 16) {
      int el = r0 + elA;
      int eln = el + 16;
      float4 tn0 = {0.f,0.f,0.f,0.f}, tn1 = {0.f,0.f,0.f,0.f};
      if (eln < span) {
        const float* tr = tf + (long)eidx_sh[eln] * DD;
        tn0 = *(const float4*)(tr + jA * 4);
        tn1 = *(const float4*)(tr + (16 + jA) * 4);
      }
      if (el < span) {
        int src = srcs_sh[el];
        int e7 = el & 7;
        *(float4*)(t_lds + el * DD + ((jA ^ e7) << 2)) = tc0;
        *(float4*)(t_lds + el * DD + ((16 + (jA ^ e7)) << 2)) = tc1;
        const float* prow = p + (long)src * DD;
        float4 p0 = *(const float4*)(prow + jA * 4);
        float4 p1 = *(const float4*)(prow + (16 + jA) * 4);
        float a = dot4(tc0, p0) + dot4(tc1, p1);
        float sims[NC];
        #pragma unroll
        for (int c = 0; c < NC; c++)
          sims[c] = dot4(tc0, ceg[c][0]) + dot4(tc1, ceg[c][1]);
        #pragma unroll
        for (int c = 0; c < NC; c++) {
          sims[c] += __shfl_xor(sims[c], 1);
          sims[c] += __shfl_xor(sims[c], 2);
          sims[c] += __shfl_xor(sims[c], 4);
          sims[c] += __shfl_xor(sims[c], 8);
        }
        a += __shfl_xor(a, 1);
        a += __shfl_xor(a, 2);
        a += __shfl_xor(a, 4);
        a += __shfl_xor(a, 8);
        if (jA == 0) {
          float best = sims[0]; int bc = 0;
          #pragma unroll
          for (int c = 1; c < NC; c++) if (sims[c] > best) { best = sims[c]; bc = c; }
          float ex = expf((a + qb_sh[src - s0]) * SCALEF);
          exf_sh[el] = ex; cli_sh[el] = bc;
          atomicAdd(&D_sh[(src - s0) * NC + bc], ex);
          atomicAdd(&C_sh[(src - s0) * NC + bc], 1);
        }
      }
      tc0 = tn0; tc1 = tn1;
    }
    __syncthreads();

    // ---- Phase B: parallel scale ----
    if (t < span) {
      int l = (srcs_sh[t] - s0) * NC + cli_sh[t];
      scl_sh[t] = exf_sh[t] * __builtin_amdgcn_rcpf(D_sh[l] * (float)C_sh[l]);
    }
    __syncthreads();

    // ---- Phase C: register-accumulated segmented sums, float4 columns ----
    for (int k = team; k < nN; k += 8) {
      float4 r = {0.f, 0.f, 0.f, 0.f};
      int e1 = offL_sh[k] + cntL_sh[k];
      for (int e = offL_sh[k]; e < e1; e++) {
        float s = scl_sh[e];
        const float4 tv = *(const float4*)(t_lds + e * DD + ((c4 ^ (e & 7)) << 2));
        r.x += s * tv.x; r.y += s * tv.y; r.z += s * tv.z; r.w += s * tv.w;
      }
      long n = s0 + k;
      *(float4*)(agg + n * DD + c4 * 4) = r;
      if (c4 == 0) {
        float ssw = 0.f; int mk = 0;
        #pragma unroll
        for (int c = 0; c < NC; c++) {
          int cc = C_sh[k * NC + c];
          if (cc > 0) { mk |= 1 << c; ssw += __builtin_amdgcn_rcpf((float)cc); }
        }
        sw[n] = ssw; msk |= mk;
      }
    }
    __syncthreads();
    s0 += nN;
  }
  if ((t & 31) == 0 && msk) atomicOr(&maskArr[b & 255], msk);
}

// --- out = relu((agg @ Wvo + sw*bvo) * inv_nne + bo); inv_nne from maskArr ---
__global__ __launch_bounds__(256) void k_out(
    const float* __restrict__ agg, const float* __restrict__ Wvo,
    const float* __restrict__ bvo, const float* __restrict__ sw,
    const float* __restrict__ bo, const int* __restrict__ maskArr,
    float* __restrict__ out) {
  __shared__ float a_lds[64 * DD];
  __shared__ float sw_lds[64];
  __shared__ int morw[4];
  int t = threadIdx.x;
  int mv = maskArr[t];
  for (int o = 1; o < 64; o <<= 1) mv |= __shfl_xor(mv, o);
  if ((t & 63) == 0) morw[t >> 6] = mv;
  long row0 = (long)blockIdx.x * 64;
  for (int it = 0; it < 8; it++) {
    int idx = (it * 256 + t) * 4;
    long r = row0 + idx / DD;
    float4 v = {0.f, 0.f, 0.f, 0.f};
    if (r < NN) v = *(const float4*)(agg + r * DD + (idx % DD));
    *(float4*)(a_lds + idx) = v;
  }
  if (t < 64) {
    long r = row0 + t;
    sw_lds[t] = (r < NN) ? sw[r] : 0.f;
  }
  __syncthreads();
  int full = morw[0] | morw[1] | morw[2] | morw[3];
  int nne = __popc(full); if (nne == 0) nne = 1;
  float inv = 1.0f / (float)nne;
  int cg = t % 32, rg = t / 32;
  int col0 = cg * 4, r0 = rg * 8;
  float acc[8][4];
  for (int r = 0; r < 8; r++) for (int c = 0; c < 4; c++) acc[r][c] = 0.f;
  for (int k = 0; k < DD; k++) {
    float4 b4 = *(const float4*)(Wvo + k * DD + col0);
    for (int r = 0; r < 8; r++) {
      float a = a_lds[(r0 + r) * DD + k];
      acc[r][0] += a * b4.x; acc[r][1] += a * b4.y;
      acc[r][2] += a * b4.z; acc[r][3] += a * b4.w;
    }
  }
  float4 bv4 = *(const float4*)(bvo + col0);
  float4 bo4 = *(const float4*)(bo + col0);
  for (int r = 0; r < 8; r++) {
    long row = row0 + r0 + r;
    if (row < NN) {
      float s = sw_lds[r0 + r];
      float4 o;
      o.x = fmaxf((acc[r][0] + s * bv4.x) * inv + bo4.x, 0.f);
      o.y = fmaxf((acc[r][1] + s * bv4.y) * inv + bo4.y, 0.f);
      o.z = fmaxf((acc[r][2] + s * bv4.z) * inv + bo4.z, 0.f);
      o.w = fmaxf((acc[r][3] + s * bv4.w) * inv + bo4.w, 0.f);
      *(float4*)(out + row * DD + col0) = o;
    }
  }
}

extern "C" void kernel_launch(void* const* d_in, const int* in_sizes, int n_in,
                              void* d_out, int out_size, void* d_ws, size_t ws_size,
                              hipStream_t stream) {
  const float* nf = (const float*)d_in[0];
  const float* tf = (const float*)d_in[1];
  // d_in[2] = context_feat: unused by the reference
  const int*   ei = (const int*)d_in[3];   // row 0 = src
  const float* Wq = (const float*)d_in[4];
  const float* bq = (const float*)d_in[5];
  const float* Wk = (const float*)d_in[6];
  const float* bk = (const float*)d_in[7];
  const float* Wv = (const float*)d_in[8];
  const float* bv = (const float*)d_in[9];
  const float* ce = (const float*)d_in[10];
  const float* Wo = (const float*)d_in[11];
  const float* bo = (const float*)d_in[12];
  float* out = (float*)d_out;

  float* ws  = (float*)d_ws;
  int*   node_cnt = (int*)(ws + OFF_NODECNT);
  int*   fill     = (int*)(ws + OFF_FILL);
  int*   maskArr  = (int*)(ws + OFF_MASK);
  int*   node_off = (int*)(ws + OFF_NODEOFF);
  int*   partial  = (int*)(ws + OFF_PARTIAL);
  int*   blockFirst = (int*)(ws + OFF_BF);
  float* bqk      = ws + OFF_BQK;
  float* bvo      = ws + OFF_BVO;
  float* wqbk     = ws + OFF_WQBK;
  float* c0       = ws + OFF_C0;
  float* Wqk      = ws + OFF_WQK;
  float* Wvo      = ws + OFF_WVO;
  float* qb       = ws + OFF_QB;
  int*   sorted   = (int*)(ws + OFF_SORTED);
  int*   srcs     = (int*)(ws + OFF_SRCS);
  float* sw       = ws + OFF_SW;
  float* p        = ws + OFF_P;   // [N,128]
  float* agg      = ws + OFF_P;   // aliased (ownership-safe)

  hipMemsetAsync(d_ws, 0, (size_t)ZERO_ELEMS * 4, stream);

  k_pre_count<<<129 + EDGE_BLKS, 256, 0, stream>>>(
      Wq, bq, Wk, bk, Wv, bv, Wo, ei, node_cnt, Wqk, bqk, Wvo, bvo, wqbk, c0);
  k_p<<<(NN + 63) / 64, 256, 0, stream>>>(nf, Wqk, bqk, wqbk, c0, p, qb);
  k_scan1<<<196, 256, 0, stream>>>(node_cnt, partial);
  k_scan2<<<1, 256, 0, stream>>>(partial);
  k_scan3<<<196, 256, 0, stream>>>(node_cnt, partial, node_off);
  k_scatter<<<EDGE_BLKS + BS_BLKS, 256, 0, stream>>>(ei, node_off, fill, sorted,
                                                     srcs, blockFirst);
  k_fused5<<<NWIN, 256, 0, stream>>>(tf, sorted, srcs, node_off, node_cnt,
                                     blockFirst, ce, p, qb, maskArr, agg, sw);
  k_out<<<(NN + 63) / 64, 256, 0, stream>>>(agg, Wvo, bvo, sw, bo, maskArr, out);
}